// Round 9
// baseline (1713.469 us; speedup 1.0000x reference)
//
#include <hip/hip_runtime.h>
#include <hip/hip_bf16.h>
#include <stdint.h>

// ---------------------------------------------------------------------------
// UNetAttention: hs(2,4096,1280) fp32; self-attention H=8, D=160; out fp32.
// GEMMs via mfma_f32_16x16x32_bf16; flash attention via mfma_f32_32x32x16_bf16
// with swapped QK^T, fully in-register P, and KV-SPLIT occupancy doubling:
// 8-wave blocks = 2 kv-half groups x 4 q-waves -> 4 waves/SIMD.
// ---------------------------------------------------------------------------

using bf16x8 = __attribute__((ext_vector_type(8))) short;  // 8 bf16 in 4 VGPRs
using f32x4  = __attribute__((ext_vector_type(4))) float;  // 16x16 MFMA C/D
using f32x16 = __attribute__((ext_vector_type(16))) float; // 32x32 MFMA C/D

__device__ __forceinline__ short f2bf(float f) {
    union { float f; uint32_t u; } v; v.f = f;
    uint32_t r = v.u + 0x7fffu + ((v.u >> 16) & 1u);   // RNE
    return (short)(r >> 16);
}

// async global->LDS DMA, 16B per lane.  LDS dest = wave-uniform base + lane*16.
__device__ __forceinline__ void async16(const short* g, short* l) {
    __builtin_amdgcn_global_load_lds(
        (const __attribute__((address_space(1))) void*)g,
        (__attribute__((address_space(3))) void*)l, 16, 0, 0);
}

// ---------------------------------------------------------------------------
// hs fp32 -> bf16 (row-major, for DMA-staged QKV GEMM A)
// ---------------------------------------------------------------------------
__global__ __launch_bounds__(256) void cast_hs(
    const float* __restrict__ hs, short* __restrict__ out)
{
    int i = (blockIdx.x * 256 + threadIdx.x) * 4;
    float4 v = *(const float4*)&hs[i];
    short4 s; s.x = f2bf(v.x); s.y = f2bf(v.y); s.z = f2bf(v.z); s.w = f2bf(v.w);
    *(short4*)&out[i] = s;
}

// ---------------------------------------------------------------------------
// Weight transpose+cast: w[k][n] fp32 -> wT[n][k] bf16.
// ---------------------------------------------------------------------------
__global__ __launch_bounds__(256) void transpose_w(
    const float* __restrict__ w0, const float* __restrict__ w1,
    const float* __restrict__ w2, const float* __restrict__ w3,
    short* __restrict__ wqkvT, short* __restrict__ woutT)
{
    __shared__ float tile[32][33];
    int z = blockIdx.z;
    const float* src = (z == 0) ? w0 : (z == 1) ? w1 : (z == 2) ? w2 : w3;
    short* dst = (z == 3) ? woutT : (wqkvT + (long)z * 1280 * 1280);
    int k0 = blockIdx.x * 32, n0 = blockIdx.y * 32;
    int t = threadIdx.x, r = t >> 5, c = t & 31;
#pragma unroll
    for (int i = 0; i < 4; i++)
        tile[r + i * 8][c] = src[(long)(k0 + r + i * 8) * 1280 + n0 + c];
    __syncthreads();
#pragma unroll
    for (int i = 0; i < 4; i++)
        dst[(long)(n0 + r + i * 8) * 1280 + k0 + c] = f2bf(tile[c][r + i * 8]);
}

// ---------------------------------------------------------------------------
// v_h [bh][4096][160] bf16 -> v_t [bh][160][4096] bf16
// ---------------------------------------------------------------------------
__global__ __launch_bounds__(256) void transpose_v(
    const short* __restrict__ v, short* __restrict__ vt)
{
    __shared__ short tile[32][33];
    int s0 = blockIdx.x * 32, d0 = blockIdx.y * 32;
    long bh = blockIdx.z;
    const short* src = v + bh * 4096 * 160;
    short* dst = vt + bh * 160 * 4096;
    int t = threadIdx.x, r = t >> 5, c = t & 31;
#pragma unroll
    for (int i = 0; i < 4; i++)
        tile[r + i * 8][c] = src[(s0 + r + i * 8) * 160 + d0 + c];
    __syncthreads();
#pragma unroll
    for (int i = 0; i < 4; i++)
        dst[(d0 + r + i * 8) * 4096 + s0 + c] = tile[c][r + i * 8];
}

// ---------------------------------------------------------------------------
// 128x128 MFMA GEMM, BK=64, global_load_lds staging, XOR-swizzled LDS.
// MODE 0: QKV epilogue (scatter to q_h/k_h/v_h; q pre-scaled by scale*log2e).
// MODE 1: out-proj epilogue (fp32 + bias).
// ---------------------------------------------------------------------------
template <int MODE>
__global__ __launch_bounds__(256, 3) void gemm_k(
    const short* __restrict__ A, const short* __restrict__ BT,
    short* __restrict__ q_h, short* __restrict__ k_h, short* __restrict__ v_h,
    float* __restrict__ outp, const float* __restrict__ bias)
{
    __shared__ __align__(16) short A_lds[128 * 64];
    __shared__ __align__(16) short B_lds[128 * 64];

    int t = threadIdx.x, wave = t >> 6, lane = t & 63;
    int quad = lane >> 4, l15 = lane & 15, h7 = l15 & 7;
    int wr = wave >> 1, wc = wave & 1;
    int m0 = blockIdx.y * 128, n0 = blockIdx.x * 128;

    f32x4 acc[4][4] = {};

    for (int kt = 0; kt < 1280; kt += 64) {
        __syncthreads();
#pragma unroll
        for (int i = 0; i < 4; i++) {
            int chunk = wave * 4 + i;
            int c = chunk * 64 + lane;
            int row = c >> 3, j = (c & 7) ^ (row & 7);
            async16(A  + (long)(m0 + row) * 1280 + kt + j * 8, A_lds + chunk * 512);
            async16(BT + (long)(n0 + row) * 1280 + kt + j * 8, B_lds + chunk * 512);
        }
        __syncthreads();

#pragma unroll
        for (int dk = 0; dk < 2; dk++) {
            bf16x8 a[4], b[4];
#pragma unroll
            for (int mi = 0; mi < 4; mi++) {
                int row = wr * 64 + mi * 16 + l15;
                a[mi] = *(const bf16x8*)&A_lds[row * 64 + ((dk * 4 + quad) ^ h7) * 8];
            }
#pragma unroll
            for (int ni = 0; ni < 4; ni++) {
                int row = wc * 64 + ni * 16 + l15;
                b[ni] = *(const bf16x8*)&B_lds[row * 64 + ((dk * 4 + quad) ^ h7) * 8];
            }
#pragma unroll
            for (int mi = 0; mi < 4; mi++)
#pragma unroll
                for (int ni = 0; ni < 4; ni++)
                    acc[mi][ni] = __builtin_amdgcn_mfma_f32_16x16x32_bf16(
                        a[mi], b[ni], acc[mi][ni], 0, 0, 0);
        }
    }

    const float SL2E = 0.07905694150420949f * 1.4426950408889634f;
#pragma unroll
    for (int mi = 0; mi < 4; mi++) {
#pragma unroll
        for (int ni = 0; ni < 4; ni++) {
#pragma unroll
            for (int r = 0; r < 4; r++) {
                int gr = m0 + wr * 64 + mi * 16 + quad * 4 + r;
                int gc = n0 + wc * 64 + ni * 16 + l15;
                float val = acc[mi][ni][r];
                if (MODE == 0) {
                    int which = gc / 1280;
                    int c1 = gc - which * 1280;
                    int hh = c1 / 160, d = c1 - hh * 160;
                    int b_ = gr >> 12, s = gr & 4095;
                    long addr = (((long)(b_ * 8 + hh)) * 4096 + s) * 160 + d;
                    if (which == 0) val *= SL2E;   // fold scale*log2e into Q
                    short* dst = (which == 0) ? q_h : (which == 1) ? k_h : v_h;
                    dst[addr] = f2bf(val);
                } else {
                    outp[(long)gr * 1280 + gc] = val + bias[gc];
                }
            }
        }
    }
}

// ---------------------------------------------------------------------------
// Flash attention, 32x32x16 MFMA, swapped QK^T, in-register P, KV-SPLIT.
//
// Block = 512 threads = 8 waves = 2 kv-half groups (kvh = wave>>2) x 4 q-waves
// (qw = wave&3).  Group kvh processes k in [kvh*2048, (kvh+1)*2048) for the
// same 128 q-rows, with its OWN K/V LDS set -> per-wave loop is 32 iters.
// Total waves = 4096 -> 16/CU -> 4 waves/SIMD.  LDS = flat 81920 B
// (2 x 20480-short group sets); 2 blocks/CU = exactly 160 KiB.
//
// Per-wave math identical to round 7 (verified): swapped QK^T dual-chain,
// p = exp2(s-16) (fixed max -> kv-halves combine by plain addition),
// cvt_pk + permlane32_swap A-frag assembly, raw-e row-sum.
//
// Epilogue (round-8 capacity bug FIXED): two-phase LDS exchange.
//   phase 1: group1 writes lsum (128 floats) -> barrier -> group0 reads
//            -> barrier (read drained before region reuse).
//   phase 2: group1 writes o[] plane-major over the WHOLE 81920 B:
//            plane p=ct*4+rr at exO[p*1024 + qw*256 + lane*4] (float4);
//            4x64x80 floats = 20480 = exact fit; 16B lane stride -> each
//            8-lane write/read phase covers all 32 banks (conflict-free).
//            -> barrier -> group0 adds, normalizes, stores.
// ---------------------------------------------------------------------------
__global__ __launch_bounds__(512, 4) void flash_k(
    const short* __restrict__ q_h, const short* __restrict__ k_h,
    const short* __restrict__ v_t, short* __restrict__ attn_out)
{
    __shared__ __align__(16) short LDS[40960];   // 81920 B flat
    // per-group set (20480 shorts): Kb128 (8192) | Kb32 (2048) | Vb (10240)

    int t = threadIdx.x, wave = t >> 6, lane = t & 63;
    int l31 = lane & 31, hi = lane >> 5;
    int qw = wave & 3, kvh = wave >> 2;
    int qt = blockIdx.x;
    long bh = blockIdx.y;
    int b = (int)(bh >> 3), h = (int)(bh & 7);

    short* Kb128 = LDS + kvh * 20480;
    short* Kb32  = Kb128 + 8192;
    short* Vb    = Kb128 + 10240;
    long kbase = bh * 4096 + kvh * 2048;    // this group's k origin (rows of K)

    // Q B-frags: lane holds Q[q = qt*128 + qw*32 + l31][d = dk*16 + hi*8 + 0..7]
    bf16x8 qf[10];
    {
        const short* qg = q_h + (bh * 4096 + qt * 128 + qw * 32 + l31) * 160;
#pragma unroll
        for (int dk = 0; dk < 10; dk++)
            qf[dk] = *(const bf16x8*)&qg[dk * 16 + hi * 8];
    }

    // per-wave staging (within its group): 5 K loads, 5 V loads per call
    auto stageK = [&](int k0) {
        const short* kg = k_h + (kbase + k0) * 160;
#pragma unroll
        for (int i = 0; i < 4; i++) {          // Kb128: 16 issues/group
            int chunk = qw * 4 + i;
            int c = chunk * 64 + lane;
            int row = c >> 4, j = (c & 15) ^ (row & 7);
            async16(kg + row * 160 + j * 8, Kb128 + chunk * 512);
        }
        {                                       // Kb32: 4 issues/group
            int row = qw * 16 + (lane >> 2);
            int r31 = row & 31;
            int j = (lane & 3) ^ (((r31 >> 1) & 3) ^ ((r31 >> 3) & 3));
            async16(kg + row * 160 + 128 + j * 8, Kb32 + qw * 512);
        }
    };
    auto stageV = [&](int k0) {
#pragma unroll
        for (int i = 0; i < 5; i++) {          // Vb rows 0..159: 20 issues/group
            int chunk = qw * 5 + i;
            int c = chunk * 64 + lane;
            int row = c >> 3, j = (c & 7) ^ (row & 7);
            async16(v_t + (bh * 160 + row) * 4096 + (kvh * 2048 + k0) + j * 8,
                    Vb + chunk * 512);
        }
    };

    f32x16 o[5] = {};    // O accumulators: o[ct][reg], d = ct*32+l31
    float lacc = 0.f;    // row-sum partial (own 32-k slice per tile)
    int sk31 = ((l31 >> 1) & 3) ^ ((l31 >> 3) & 3);   // Kb32 read swizzle

    // prologue: K(0)+V(0) in flight; wait only K(0) (own 5 oldest), barrier.
    stageK(0);
    stageV(0);
    asm volatile("s_waitcnt vmcnt(5)" ::: "memory");   // K(0) landed (own)
    asm volatile("s_waitcnt lgkmcnt(0)" ::: "memory");
    __builtin_amdgcn_s_barrier();

    for (int k0 = 0; k0 < 2048; k0 += 64) {
        uint32_t pw[4][4];   // PV A-frag words, pw[g][w]: k = 16g+8hi+2w+{0,1}

        // ---- QK^T (swapped, dual-chain) + softmax + frag assembly ----
#pragma unroll
        for (int kt = 0; kt < 2; kt++) {
            f32x16 sa = {}, sb = {};
            __builtin_amdgcn_s_setprio(1);
#pragma unroll
            for (int dk = 0; dk < 8; dk += 2) {
                bf16x8 ka0 = *(const bf16x8*)
                    &Kb128[(kt * 32 + l31) * 128 + (((dk * 2 + hi) ^ (l31 & 7)) * 8)];
                bf16x8 ka1 = *(const bf16x8*)
                    &Kb128[(kt * 32 + l31) * 128 + ((((dk + 1) * 2 + hi) ^ (l31 & 7)) * 8)];
                sa = __builtin_amdgcn_mfma_f32_32x32x16_bf16(ka0, qf[dk],     sa, 0, 0, 0);
                sb = __builtin_amdgcn_mfma_f32_32x32x16_bf16(ka1, qf[dk + 1], sb, 0, 0, 0);
            }
            {
                bf16x8 ka8 = *(const bf16x8*)
                    &Kb32[(kt * 32 + l31) * 32 + (((0 * 2 + hi) ^ sk31) * 8)];
                bf16x8 ka9 = *(const bf16x8*)
                    &Kb32[(kt * 32 + l31) * 32 + (((1 * 2 + hi) ^ sk31) * 8)];
                sa = __builtin_amdgcn_mfma_f32_32x32x16_bf16(ka8, qf[8], sa, 0, 0, 0);
                sb = __builtin_amdgcn_mfma_f32_32x32x16_bf16(ka9, qf[9], sb, 0, 0, 0);
            }
            __builtin_amdgcn_s_setprio(0);
            f32x16 s = sa + sb;

            // p = exp2(s-16); reg -> k = (reg&3)+8*(reg>>2)+4*hi (+kt*32)
            uint32_t u[4][2];
#pragma unroll
            for (int rg = 0; rg < 4; rg++) {
                float e0 = exp2f(s[rg * 4 + 0] - 16.f);
                float e1 = exp2f(s[rg * 4 + 1] - 16.f);
                float e2 = exp2f(s[rg * 4 + 2] - 16.f);
                float e3 = exp2f(s[rg * 4 + 3] - 16.f);
                uint32_t pk0, pk1;
                asm("v_cvt_pk_bf16_f32 %0, %1, %2" : "=v"(pk0) : "v"(e0), "v"(e1));
                asm("v_cvt_pk_bf16_f32 %0, %1, %2" : "=v"(pk1) : "v"(e2), "v"(e3));
                u[rg][0] = pk0; u[rg][1] = pk1;
                lacc += (e0 + e1) + (e2 + e3);   // raw-e row-sum (tree)
            }
            // A-frag assembly: one permlane32_swap fills words c and c+2
#pragma unroll
            for (int ksl = 0; ksl < 2; ksl++)
#pragma unroll
                for (int c = 0; c < 2; c++) {
                    auto r = __builtin_amdgcn_permlane32_swap(
                        u[2 * ksl][c], u[2 * ksl + 1][c], false, false);
                    pw[kt * 2 + ksl][c]     = (uint32_t)r[0];
                    pw[kt * 2 + ksl][c + 2] = (uint32_t)r[1];
                }
        }

        // V(t) landed (only V(t) outstanding); all waves done reading K(t)
        asm volatile("s_waitcnt vmcnt(0)" ::: "memory");
        asm volatile("s_waitcnt lgkmcnt(0)" ::: "memory");
        __builtin_amdgcn_s_barrier();                      // B

        if (k0 + 64 < 2048) stageK(k0 + 64);   // lands under PV(t)

        // ---- O += P V ----
        __builtin_amdgcn_s_setprio(1);
#pragma unroll
        for (int ks = 0; ks < 4; ks++) {
            union { uint32_t w[4]; bf16x8 v; } ap;
            ap.w[0] = pw[ks][0]; ap.w[1] = pw[ks][1];
            ap.w[2] = pw[ks][2]; ap.w[3] = pw[ks][3];
#pragma unroll
            for (int ct = 0; ct < 5; ct++) {
                int row = ct * 32 + l31;
                bf16x8 bv = *(const bf16x8*)
                    &Vb[row * 64 + (((ks * 2 + hi) ^ (row & 7)) * 8)];
                o[ct] = __builtin_amdgcn_mfma_f32_32x32x16_bf16(ap.v, bv, o[ct], 0, 0, 0);
            }
        }
        __builtin_amdgcn_s_setprio(0);

        // K(t+1) landed (only K(t+1) outstanding); all waves done with V(t)
        asm volatile("s_waitcnt vmcnt(0)" ::: "memory");
        asm volatile("s_waitcnt lgkmcnt(0)" ::: "memory");
        __builtin_amdgcn_s_barrier();                      // E

        if (k0 + 64 < 2048) stageV(k0 + 64);   // lands under QK(t+1)+SM(t+1)
    }

    // ---- epilogue: combine kv-halves via LDS (two-phase), normalize ----
    // per-wave fold of own row-sum halves: lsum valid for q=l31 on all lanes
    float lsum = lacc + __shfl_xor(lacc, 32);

    // phase 1: lsum exchange (128 floats at LDS base)
    float* exL = (float*)LDS;
    if (kvh == 1 && hi == 0) exL[qw * 32 + l31] = lsum;
    asm volatile("s_waitcnt lgkmcnt(0)" ::: "memory");
    __builtin_amdgcn_s_barrier();
    float lsum_o = 0.f;
    if (kvh == 0) lsum_o = exL[qw * 32 + l31];
    asm volatile("s_waitcnt lgkmcnt(0)" ::: "memory");
    __builtin_amdgcn_s_barrier();    // reads drained before region reuse

    // phase 2: o[] exchange, plane-major over the whole 81920 B
    float* exO = (float*)LDS;        // 20480 floats = 4qw x 64lane x 80
    if (kvh == 1) {
#pragma unroll
        for (int ct = 0; ct < 5; ct++)
#pragma unroll
            for (int rr = 0; rr < 4; rr++) {
                int plane = ct * 4 + rr;
                float4 v4 = { o[ct][rr * 4 + 0], o[ct][rr * 4 + 1],
                              o[ct][rr * 4 + 2], o[ct][rr * 4 + 3] };
                *(float4*)&exO[plane * 1024 + qw * 256 + lane * 4] = v4;
            }
    }
    asm volatile("s_waitcnt lgkmcnt(0)" ::: "memory");
    __builtin_amdgcn_s_barrier();

    if (kvh == 0) {
#pragma unroll
        for (int ct = 0; ct < 5; ct++)
#pragma unroll
            for (int rr = 0; rr < 4; rr++) {
                int plane = ct * 4 + rr;
                float4 v4 = *(const float4*)&exO[plane * 1024 + qw * 256 + lane * 4];
                o[ct][rr * 4 + 0] += v4.x; o[ct][rr * 4 + 1] += v4.y;
                o[ct][rr * 4 + 2] += v4.z; o[ct][rr * 4 + 3] += v4.w;
            }
        float inv = 1.0f / (lsum + lsum_o);   // valid for q = l31 on every lane
        float iv[16];
#pragma unroll
        for (int r = 0; r < 16; r++)
            iv[r] = __shfl(inv, (r & 3) + 8 * (r >> 2) + 4 * hi);

#pragma unroll
        for (int ct = 0; ct < 5; ct++)
#pragma unroll
            for (int r = 0; r < 16; r++) {
                int crow = (r & 3) + 8 * (r >> 2) + 4 * hi;
                int gr = b * 4096 + qt * 128 + qw * 32 + crow;
                int gc = h * 160 + ct * 32 + l31;
                attn_out[(long)gr * 1280 + gc] = f2bf(o[ct][r] * iv[r]);
            }
    }
}

// ---------------------------------------------------------------------------
// Launch
// ---------------------------------------------------------------------------
extern "C" void kernel_launch(void* const* d_in, const int* in_sizes, int n_in,
                              void* d_out, int out_size, void* d_ws, size_t ws_size,
                              hipStream_t stream)
{
    const float* hs = (const float*)d_in[0];
    const float* wq = (const float*)d_in[1];
    const float* wk = (const float*)d_in[2];
    const float* wv = (const float*)d_in[3];
    const float* wo = (const float*)d_in[4];
    const float* bo = (const float*)d_in[5];
    float* out = (float*)d_out;

    // workspace layout (bytes), ~97 MB total
    char* ws = (char*)d_ws;
    short* wqkvT = (short*)(ws + 0);            // 3840*1280*2 = 9,830,400
    short* woutT = (short*)(ws + 9830400);      // 1280*1280*2 = 3,276,800
    short* q_h   = (short*)(ws + 13107200);     // 16*4096*160*2 = 20,971,520
    short* k_h   = (short*)(ws + 34078720);
    short* v_t   = (short*)(ws + 55050240);     // also hs_bf before transpose_v
    short* v_h   = (short*)(ws + 76021760);     // aliased with attn (disjoint lifetimes)
    short* attn  = v_h;
    short* hs_bf = v_t;   // hs_bf dead before v_t is born

    cast_hs<<<10240, 256, 0, stream>>>(hs, hs_bf);
    transpose_w<<<dim3(40, 40, 4), 256, 0, stream>>>(wq, wk, wv, wo, wqkvT, woutT);
    gemm_k<0><<<dim3(30, 64), 256, 0, stream>>>(hs_bf, wqkvT, q_h, k_h, v_h,
                                                nullptr, nullptr);
    transpose_v<<<dim3(128, 5, 16), 256, 0, stream>>>(v_h, v_t);
    flash_k<<<dim3(32, 16), 512, 0, stream>>>(q_h, k_h, v_t, attn);
    gemm_k<1><<<dim3(10, 64), 256, 0, stream>>>(attn, woutT, nullptr, nullptr,
                                                nullptr, out, bo);
}

// Round 10
// 445.325 us; speedup vs baseline: 3.8477x; 3.8477x over previous
//
#include <hip/hip_runtime.h>
#include <hip/hip_bf16.h>
#include <stdint.h>

// ---------------------------------------------------------------------------
// UNetAttention: hs(2,4096,1280) fp32; self-attention H=8, D=160; out fp32.
// GEMMs via mfma_f32_16x16x32_bf16; flash attention via mfma_f32_32x32x16_bf16
// with swapped QK^T, fully in-register P, and KV-SPLIT occupancy doubling:
// 8-wave blocks = 2 kv-half groups x 4 q-waves -> 4 waves/SIMD.
// ---------------------------------------------------------------------------

using bf16x8 = __attribute__((ext_vector_type(8))) short;  // 8 bf16 in 4 VGPRs
using f32x4  = __attribute__((ext_vector_type(4))) float;  // 16x16 MFMA C/D
using f32x16 = __attribute__((ext_vector_type(16))) float; // 32x32 MFMA C/D

__device__ __forceinline__ short f2bf(float f) {
    union { float f; uint32_t u; } v; v.f = f;
    uint32_t r = v.u + 0x7fffu + ((v.u >> 16) & 1u);   // RNE
    return (short)(r >> 16);
}

// async global->LDS DMA, 16B per lane.  LDS dest = wave-uniform base + lane*16.
__device__ __forceinline__ void async16(const short* g, short* l) {
    __builtin_amdgcn_global_load_lds(
        (const __attribute__((address_space(1))) void*)g,
        (__attribute__((address_space(3))) void*)l, 16, 0, 0);
}

// ---------------------------------------------------------------------------
// hs fp32 -> bf16 (row-major, for DMA-staged QKV GEMM A)
// ---------------------------------------------------------------------------
__global__ __launch_bounds__(256) void cast_hs(
    const float* __restrict__ hs, short* __restrict__ out)
{
    int i = (blockIdx.x * 256 + threadIdx.x) * 4;
    float4 v = *(const float4*)&hs[i];
    short4 s; s.x = f2bf(v.x); s.y = f2bf(v.y); s.z = f2bf(v.z); s.w = f2bf(v.w);
    *(short4*)&out[i] = s;
}

// ---------------------------------------------------------------------------
// Weight transpose+cast: w[k][n] fp32 -> wT[n][k] bf16.
// ---------------------------------------------------------------------------
__global__ __launch_bounds__(256) void transpose_w(
    const float* __restrict__ w0, const float* __restrict__ w1,
    const float* __restrict__ w2, const float* __restrict__ w3,
    short* __restrict__ wqkvT, short* __restrict__ woutT)
{
    __shared__ float tile[32][33];
    int z = blockIdx.z;
    const float* src = (z == 0) ? w0 : (z == 1) ? w1 : (z == 2) ? w2 : w3;
    short* dst = (z == 3) ? woutT : (wqkvT + (long)z * 1280 * 1280);
    int k0 = blockIdx.x * 32, n0 = blockIdx.y * 32;
    int t = threadIdx.x, r = t >> 5, c = t & 31;
#pragma unroll
    for (int i = 0; i < 4; i++)
        tile[r + i * 8][c] = src[(long)(k0 + r + i * 8) * 1280 + n0 + c];
    __syncthreads();
#pragma unroll
    for (int i = 0; i < 4; i++)
        dst[(long)(n0 + r + i * 8) * 1280 + k0 + c] = f2bf(tile[c][r + i * 8]);
}

// ---------------------------------------------------------------------------
// v_h [bh][4096][160] bf16 -> v_t [bh][160][4096] bf16
// ---------------------------------------------------------------------------
__global__ __launch_bounds__(256) void transpose_v(
    const short* __restrict__ v, short* __restrict__ vt)
{
    __shared__ short tile[32][33];
    int s0 = blockIdx.x * 32, d0 = blockIdx.y * 32;
    long bh = blockIdx.z;
    const short* src = v + bh * 4096 * 160;
    short* dst = vt + bh * 160 * 4096;
    int t = threadIdx.x, r = t >> 5, c = t & 31;
#pragma unroll
    for (int i = 0; i < 4; i++)
        tile[r + i * 8][c] = src[(s0 + r + i * 8) * 160 + d0 + c];
    __syncthreads();
#pragma unroll
    for (int i = 0; i < 4; i++)
        dst[(d0 + r + i * 8) * 4096 + s0 + c] = tile[c][r + i * 8];
}

// ---------------------------------------------------------------------------
// 128x128 MFMA GEMM, BK=64, global_load_lds staging, XOR-swizzled LDS.
// MODE 0: QKV epilogue (scatter to q_h/k_h/v_h; q pre-scaled by scale*log2e).
// MODE 1: out-proj epilogue (fp32 + bias).
// ---------------------------------------------------------------------------
template <int MODE>
__global__ __launch_bounds__(256, 3) void gemm_k(
    const short* __restrict__ A, const short* __restrict__ BT,
    short* __restrict__ q_h, short* __restrict__ k_h, short* __restrict__ v_h,
    float* __restrict__ outp, const float* __restrict__ bias)
{
    __shared__ __align__(16) short A_lds[128 * 64];
    __shared__ __align__(16) short B_lds[128 * 64];

    int t = threadIdx.x, wave = t >> 6, lane = t & 63;
    int quad = lane >> 4, l15 = lane & 15, h7 = l15 & 7;
    int wr = wave >> 1, wc = wave & 1;
    int m0 = blockIdx.y * 128, n0 = blockIdx.x * 128;

    f32x4 acc[4][4] = {};

    for (int kt = 0; kt < 1280; kt += 64) {
        __syncthreads();
#pragma unroll
        for (int i = 0; i < 4; i++) {
            int chunk = wave * 4 + i;
            int c = chunk * 64 + lane;
            int row = c >> 3, j = (c & 7) ^ (row & 7);
            async16(A  + (long)(m0 + row) * 1280 + kt + j * 8, A_lds + chunk * 512);
            async16(BT + (long)(n0 + row) * 1280 + kt + j * 8, B_lds + chunk * 512);
        }
        __syncthreads();

#pragma unroll
        for (int dk = 0; dk < 2; dk++) {
            bf16x8 a[4], b[4];
#pragma unroll
            for (int mi = 0; mi < 4; mi++) {
                int row = wr * 64 + mi * 16 + l15;
                a[mi] = *(const bf16x8*)&A_lds[row * 64 + ((dk * 4 + quad) ^ h7) * 8];
            }
#pragma unroll
            for (int ni = 0; ni < 4; ni++) {
                int row = wc * 64 + ni * 16 + l15;
                b[ni] = *(const bf16x8*)&B_lds[row * 64 + ((dk * 4 + quad) ^ h7) * 8];
            }
#pragma unroll
            for (int mi = 0; mi < 4; mi++)
#pragma unroll
                for (int ni = 0; ni < 4; ni++)
                    acc[mi][ni] = __builtin_amdgcn_mfma_f32_16x16x32_bf16(
                        a[mi], b[ni], acc[mi][ni], 0, 0, 0);
        }
    }

    const float SL2E = 0.07905694150420949f * 1.4426950408889634f;
#pragma unroll
    for (int mi = 0; mi < 4; mi++) {
#pragma unroll
        for (int ni = 0; ni < 4; ni++) {
#pragma unroll
            for (int r = 0; r < 4; r++) {
                int gr = m0 + wr * 64 + mi * 16 + quad * 4 + r;
                int gc = n0 + wc * 64 + ni * 16 + l15;
                float val = acc[mi][ni][r];
                if (MODE == 0) {
                    int which = gc / 1280;
                    int c1 = gc - which * 1280;
                    int hh = c1 / 160, d = c1 - hh * 160;
                    int b_ = gr >> 12, s = gr & 4095;
                    long addr = (((long)(b_ * 8 + hh)) * 4096 + s) * 160 + d;
                    if (which == 0) val *= SL2E;   // fold scale*log2e into Q
                    short* dst = (which == 0) ? q_h : (which == 1) ? k_h : v_h;
                    dst[addr] = f2bf(val);
                } else {
                    outp[(long)gr * 1280 + gc] = val + bias[gc];
                }
            }
        }
    }
}

// ---------------------------------------------------------------------------
// Flash attention, 32x32x16 MFMA, swapped QK^T, in-register P, KV-SPLIT.
//
// Block = 512 threads = 8 waves = 2 kv-half groups (kvh = wave>>2) x 4 q-waves
// (qw = wave&3).  Group kvh processes k in [kvh*2048, (kvh+1)*2048) for the
// same 128 q-rows, with its OWN K/V LDS set -> per-wave loop is 32 iters.
// Total waves = 4096 -> 16/CU -> 4 waves/SIMD.  LDS = flat 81920 B
// (2 x 20480-short group sets); 2 blocks/CU = exactly 160 KiB.
//
// __launch_bounds__(512, 2): round 9's (512,4) was interpreted as 4 BLOCKS/CU
// (8 waves/SIMD) -> VGPR capped at 64 -> o[] spilled -> 3.3 GB scratch traffic
// and 7x regression.  (512,2) = 2 blocks/CU = 4 waves/SIMD = 128-VGPR cap,
// which fits this body (~120 VGPR).  LDS independently enforces <=2 blocks/CU.
//
// Per-wave math identical to round 7 (verified): swapped QK^T dual-chain,
// p = exp2(s-16) (fixed max -> kv-halves combine by plain addition),
// cvt_pk + permlane32_swap A-frag assembly, raw-e row-sum.
//
// Epilogue: two-phase LDS exchange (verified round 9):
//   phase 1: group1 writes lsum (128 floats) -> barrier -> group0 reads
//            -> barrier.
//   phase 2: group1 writes o[] plane-major over the WHOLE 81920 B
//            (4x64x80 floats = exact fit; 16B lane stride, conflict-free)
//            -> barrier -> group0 adds, normalizes, stores.
// ---------------------------------------------------------------------------
__global__ __launch_bounds__(512, 2) void flash_k(
    const short* __restrict__ q_h, const short* __restrict__ k_h,
    const short* __restrict__ v_t, short* __restrict__ attn_out)
{
    __shared__ __align__(16) short LDS[40960];   // 81920 B flat
    // per-group set (20480 shorts): Kb128 (8192) | Kb32 (2048) | Vb (10240)

    int t = threadIdx.x, wave = t >> 6, lane = t & 63;
    int l31 = lane & 31, hi = lane >> 5;
    int qw = wave & 3, kvh = wave >> 2;
    int qt = blockIdx.x;
    long bh = blockIdx.y;
    int b = (int)(bh >> 3), h = (int)(bh & 7);

    short* Kb128 = LDS + kvh * 20480;
    short* Kb32  = Kb128 + 8192;
    short* Vb    = Kb128 + 10240;
    long kbase = bh * 4096 + kvh * 2048;    // this group's k origin (rows of K)

    // Q B-frags: lane holds Q[q = qt*128 + qw*32 + l31][d = dk*16 + hi*8 + 0..7]
    bf16x8 qf[10];
    {
        const short* qg = q_h + (bh * 4096 + qt * 128 + qw * 32 + l31) * 160;
#pragma unroll
        for (int dk = 0; dk < 10; dk++)
            qf[dk] = *(const bf16x8*)&qg[dk * 16 + hi * 8];
    }

    // per-wave staging (within its group): 5 K loads, 5 V loads per call
    auto stageK = [&](int k0) {
        const short* kg = k_h + (kbase + k0) * 160;
#pragma unroll
        for (int i = 0; i < 4; i++) {          // Kb128: 16 issues/group
            int chunk = qw * 4 + i;
            int c = chunk * 64 + lane;
            int row = c >> 4, j = (c & 15) ^ (row & 7);
            async16(kg + row * 160 + j * 8, Kb128 + chunk * 512);
        }
        {                                       // Kb32: 4 issues/group
            int row = qw * 16 + (lane >> 2);
            int r31 = row & 31;
            int j = (lane & 3) ^ (((r31 >> 1) & 3) ^ ((r31 >> 3) & 3));
            async16(kg + row * 160 + 128 + j * 8, Kb32 + qw * 512);
        }
    };
    auto stageV = [&](int k0) {
#pragma unroll
        for (int i = 0; i < 5; i++) {          // Vb rows 0..159: 20 issues/group
            int chunk = qw * 5 + i;
            int c = chunk * 64 + lane;
            int row = c >> 3, j = (c & 7) ^ (row & 7);
            async16(v_t + (bh * 160 + row) * 4096 + (kvh * 2048 + k0) + j * 8,
                    Vb + chunk * 512);
        }
    };

    f32x16 o[5] = {};    // O accumulators: o[ct][reg], d = ct*32+l31
    float lacc = 0.f;    // row-sum partial (own 32-k slice per tile)
    int sk31 = ((l31 >> 1) & 3) ^ ((l31 >> 3) & 3);   // Kb32 read swizzle

    // prologue: K(0)+V(0) in flight; wait only K(0) (own 5 oldest), barrier.
    stageK(0);
    stageV(0);
    asm volatile("s_waitcnt vmcnt(5)" ::: "memory");   // K(0) landed (own)
    asm volatile("s_waitcnt lgkmcnt(0)" ::: "memory");
    __builtin_amdgcn_s_barrier();

    for (int k0 = 0; k0 < 2048; k0 += 64) {
        uint32_t pw[4][4];   // PV A-frag words, pw[g][w]: k = 16g+8hi+2w+{0,1}

        // ---- QK^T (swapped, dual-chain) + softmax + frag assembly ----
#pragma unroll
        for (int kt = 0; kt < 2; kt++) {
            f32x16 sa = {}, sb = {};
            __builtin_amdgcn_s_setprio(1);
#pragma unroll
            for (int dk = 0; dk < 8; dk += 2) {
                bf16x8 ka0 = *(const bf16x8*)
                    &Kb128[(kt * 32 + l31) * 128 + (((dk * 2 + hi) ^ (l31 & 7)) * 8)];
                bf16x8 ka1 = *(const bf16x8*)
                    &Kb128[(kt * 32 + l31) * 128 + ((((dk + 1) * 2 + hi) ^ (l31 & 7)) * 8)];
                sa = __builtin_amdgcn_mfma_f32_32x32x16_bf16(ka0, qf[dk],     sa, 0, 0, 0);
                sb = __builtin_amdgcn_mfma_f32_32x32x16_bf16(ka1, qf[dk + 1], sb, 0, 0, 0);
            }
            {
                bf16x8 ka8 = *(const bf16x8*)
                    &Kb32[(kt * 32 + l31) * 32 + (((0 * 2 + hi) ^ sk31) * 8)];
                bf16x8 ka9 = *(const bf16x8*)
                    &Kb32[(kt * 32 + l31) * 32 + (((1 * 2 + hi) ^ sk31) * 8)];
                sa = __builtin_amdgcn_mfma_f32_32x32x16_bf16(ka8, qf[8], sa, 0, 0, 0);
                sb = __builtin_amdgcn_mfma_f32_32x32x16_bf16(ka9, qf[9], sb, 0, 0, 0);
            }
            __builtin_amdgcn_s_setprio(0);
            f32x16 s = sa + sb;

            // p = exp2(s-16); reg -> k = (reg&3)+8*(reg>>2)+4*hi (+kt*32)
            uint32_t u[4][2];
#pragma unroll
            for (int rg = 0; rg < 4; rg++) {
                float e0 = exp2f(s[rg * 4 + 0] - 16.f);
                float e1 = exp2f(s[rg * 4 + 1] - 16.f);
                float e2 = exp2f(s[rg * 4 + 2] - 16.f);
                float e3 = exp2f(s[rg * 4 + 3] - 16.f);
                uint32_t pk0, pk1;
                asm("v_cvt_pk_bf16_f32 %0, %1, %2" : "=v"(pk0) : "v"(e0), "v"(e1));
                asm("v_cvt_pk_bf16_f32 %0, %1, %2" : "=v"(pk1) : "v"(e2), "v"(e3));
                u[rg][0] = pk0; u[rg][1] = pk1;
                lacc += (e0 + e1) + (e2 + e3);   // raw-e row-sum (tree)
            }
            // A-frag assembly: one permlane32_swap fills words c and c+2
#pragma unroll
            for (int ksl = 0; ksl < 2; ksl++)
#pragma unroll
                for (int c = 0; c < 2; c++) {
                    auto r = __builtin_amdgcn_permlane32_swap(
                        u[2 * ksl][c], u[2 * ksl + 1][c], false, false);
                    pw[kt * 2 + ksl][c]     = (uint32_t)r[0];
                    pw[kt * 2 + ksl][c + 2] = (uint32_t)r[1];
                }
        }

        // V(t) landed (only V(t) outstanding); all waves done reading K(t)
        asm volatile("s_waitcnt vmcnt(0)" ::: "memory");
        asm volatile("s_waitcnt lgkmcnt(0)" ::: "memory");
        __builtin_amdgcn_s_barrier();                      // B

        if (k0 + 64 < 2048) stageK(k0 + 64);   // lands under PV(t)

        // ---- O += P V ----
        __builtin_amdgcn_s_setprio(1);
#pragma unroll
        for (int ks = 0; ks < 4; ks++) {
            union { uint32_t w[4]; bf16x8 v; } ap;
            ap.w[0] = pw[ks][0]; ap.w[1] = pw[ks][1];
            ap.w[2] = pw[ks][2]; ap.w[3] = pw[ks][3];
#pragma unroll
            for (int ct = 0; ct < 5; ct++) {
                int row = ct * 32 + l31;
                bf16x8 bv = *(const bf16x8*)
                    &Vb[row * 64 + (((ks * 2 + hi) ^ (row & 7)) * 8)];
                o[ct] = __builtin_amdgcn_mfma_f32_32x32x16_bf16(ap.v, bv, o[ct], 0, 0, 0);
            }
        }
        __builtin_amdgcn_s_setprio(0);

        // K(t+1) landed (only K(t+1) outstanding); all waves done with V(t)
        asm volatile("s_waitcnt vmcnt(0)" ::: "memory");
        asm volatile("s_waitcnt lgkmcnt(0)" ::: "memory");
        __builtin_amdgcn_s_barrier();                      // E

        if (k0 + 64 < 2048) stageV(k0 + 64);   // lands under QK(t+1)+SM(t+1)
    }

    // ---- epilogue: combine kv-halves via LDS (two-phase), normalize ----
    // per-wave fold of own row-sum halves: lsum valid for q=l31 on all lanes
    float lsum = lacc + __shfl_xor(lacc, 32);

    // phase 1: lsum exchange (128 floats at LDS base)
    float* exL = (float*)LDS;
    if (kvh == 1 && hi == 0) exL[qw * 32 + l31] = lsum;
    asm volatile("s_waitcnt lgkmcnt(0)" ::: "memory");
    __builtin_amdgcn_s_barrier();
    float lsum_o = 0.f;
    if (kvh == 0) lsum_o = exL[qw * 32 + l31];
    asm volatile("s_waitcnt lgkmcnt(0)" ::: "memory");
    __builtin_amdgcn_s_barrier();    // reads drained before region reuse

    // phase 2: o[] exchange, plane-major over the whole 81920 B
    float* exO = (float*)LDS;        // 20480 floats = 4qw x 64lane x 80
    if (kvh == 1) {
#pragma unroll
        for (int ct = 0; ct < 5; ct++)
#pragma unroll
            for (int rr = 0; rr < 4; rr++) {
                int plane = ct * 4 + rr;
                float4 v4 = { o[ct][rr * 4 + 0], o[ct][rr * 4 + 1],
                              o[ct][rr * 4 + 2], o[ct][rr * 4 + 3] };
                *(float4*)&exO[plane * 1024 + qw * 256 + lane * 4] = v4;
            }
    }
    asm volatile("s_waitcnt lgkmcnt(0)" ::: "memory");
    __builtin_amdgcn_s_barrier();

    if (kvh == 0) {
#pragma unroll
        for (int ct = 0; ct < 5; ct++)
#pragma unroll
            for (int rr = 0; rr < 4; rr++) {
                int plane = ct * 4 + rr;
                float4 v4 = *(const float4*)&exO[plane * 1024 + qw * 256 + lane * 4];
                o[ct][rr * 4 + 0] += v4.x; o[ct][rr * 4 + 1] += v4.y;
                o[ct][rr * 4 + 2] += v4.z; o[ct][rr * 4 + 3] += v4.w;
            }
        float inv = 1.0f / (lsum + lsum_o);   // valid for q = l31 on every lane
        float iv[16];
#pragma unroll
        for (int r = 0; r < 16; r++)
            iv[r] = __shfl(inv, (r & 3) + 8 * (r >> 2) + 4 * hi);

#pragma unroll
        for (int ct = 0; ct < 5; ct++)
#pragma unroll
            for (int r = 0; r < 16; r++) {
                int crow = (r & 3) + 8 * (r >> 2) + 4 * hi;
                int gr = b * 4096 + qt * 128 + qw * 32 + crow;
                int gc = h * 160 + ct * 32 + l31;
                attn_out[(long)gr * 1280 + gc] = f2bf(o[ct][r] * iv[r]);
            }
    }
}

// ---------------------------------------------------------------------------
// Launch
// ---------------------------------------------------------------------------
extern "C" void kernel_launch(void* const* d_in, const int* in_sizes, int n_in,
                              void* d_out, int out_size, void* d_ws, size_t ws_size,
                              hipStream_t stream)
{
    const float* hs = (const float*)d_in[0];
    const float* wq = (const float*)d_in[1];
    const float* wk = (const float*)d_in[2];
    const float* wv = (const float*)d_in[3];
    const float* wo = (const float*)d_in[4];
    const float* bo = (const float*)d_in[5];
    float* out = (float*)d_out;

    // workspace layout (bytes), ~97 MB total
    char* ws = (char*)d_ws;
    short* wqkvT = (short*)(ws + 0);            // 3840*1280*2 = 9,830,400
    short* woutT = (short*)(ws + 9830400);      // 1280*1280*2 = 3,276,800
    short* q_h   = (short*)(ws + 13107200);     // 16*4096*160*2 = 20,971,520
    short* k_h   = (short*)(ws + 34078720);
    short* v_t   = (short*)(ws + 55050240);     // also hs_bf before transpose_v
    short* v_h   = (short*)(ws + 76021760);     // aliased with attn (disjoint lifetimes)
    short* attn  = v_h;
    short* hs_bf = v_t;   // hs_bf dead before v_t is born

    cast_hs<<<10240, 256, 0, stream>>>(hs, hs_bf);
    transpose_w<<<dim3(40, 40, 4), 256, 0, stream>>>(wq, wk, wv, wo, wqkvT, woutT);
    gemm_k<0><<<dim3(30, 64), 256, 0, stream>>>(hs_bf, wqkvT, q_h, k_h, v_h,
                                                nullptr, nullptr);
    transpose_v<<<dim3(128, 5, 16), 256, 0, stream>>>(v_h, v_t);
    flash_k<<<dim3(32, 16), 512, 0, stream>>>(q_h, k_h, v_t, attn);
    gemm_k<1><<<dim3(10, 64), 256, 0, stream>>>(attn, woutT, nullptr, nullptr,
                                                nullptr, out, bo);
}